// Round 10
// baseline (2308.939 us; speedup 1.0000x reference)
//
#include <hip/hip_runtime.h>
#include <hip/hip_bf16.h>

// ScalarBorn: 4th-order FD scalar wave + Born scattering with CPML, MI355X.
// R24 = R23 (2115us best) + 2-ROW FRAME BLOCKS: frame rows now also merged
// pairwise (12 blocks/half-band, shared wy[10] window serves both rows: 10 w
// loads vs 18, pn/po union 6 rows vs 10 -> frame load bytes -40%). Interior
// path byte-identical to R23 (2-row-per-thread, proven -9%). Grid 888 blocks,
// bounds(256,4): residency 4 >= 3.47 needed -> one round, VGPR cap 128 fits
// frame 2-row peak (~110) -- R22's failure was cap 64, not merging itself.
// Kept: XCD banding (R15 -33%), one-round (R18), shuffle x-exchange / no LDS
// / no barriers (R19), interior 2-row traffic cut (R23 -9%).
// Falsified: 512-thr 2-row w/ cap64 (R22 +19%), direct-load x-exch (R21
// +54%), declustering (R20 +5%), full hoist (R16 +19%), cheap hoist (R17
// +5%), aggregation (R8/R10), barrier removal w/ LDS (R12/R13), load cuts
// (R7), grid.sync (R4).

constexpr int NYX  = 400;
constexpr int NS   = 4;
constexpr int NREC = 100;
constexpr int NT   = 300;
constexpr int PAD  = 22;
constexpr int NP   = 444;
constexpr int NP2  = NP * NP;          // 197136
constexpr int SNP2 = NS * NP2;         // 788544
constexpr int NBLK = 888;              // 8 half-bands x (12 frame2 + 99 int2)
constexpr float DT    = 0.0005f;
constexpr float INVH  = 0.2f;
constexpr float INVH2 = 0.04f;
constexpr float C1A = 1.0f / 12.0f;
constexpr float C1B = 2.0f / 3.0f;
constexpr float C2A = -1.0f / 12.0f;
constexpr float C2B = 4.0f / 3.0f;
constexpr float C2C = -2.5f;

// interleaved state: element (b,s) pair for grid index idx lives at [2*idx, 2*idx+1]
__device__ __align__(16) float g_w[2][2 * SNP2];   // wavefield ping-pong
__device__ __align__(16) float g_px[2][2 * SNP2];  // psi_x dbuf
__device__ __align__(16) float g_py[2][2 * SNP2];  // psi_y dbuf
__device__ __align__(16) float g_zx[2 * SNP2];     // zeta_x
__device__ __align__(16) float g_zy[2 * SNP2];     // zeta_y
__device__ __align__(16) float g_vb[2 * NP2];      // (v2dt2, bscale) pairs
__device__ float g_pa[NP];
__device__ float g_pb[NP];
__device__ float g_fbg[NT * NS];
__device__ float g_fsc[NT * NS];
__device__ int   g_spos[2 * NS];
__device__ int   g_mode;               // 1 = bf16 io, 0 = f32 io

__device__ __forceinline__ int clampi(int v, int lo, int hi) {
    return v < lo ? lo : (v > hi ? hi : v);
}
__device__ __forceinline__ float in_ld(const void* p, int i) {
    if (g_mode) return __bfloat162float(((const __hip_bfloat16*)p)[i]);
    return ((const float*)p)[i];
}
__device__ __forceinline__ void out_st(void* p, int i, float v) {
    if (g_mode) ((__hip_bfloat16*)p)[i] = __float2bfloat16(v);
    else        ((float*)p)[i] = v;
}
// float4 = (b0,s0,b1,s1) at row yy, col pair ip of shot s; 0 if row OOB
__device__ __forceinline__ float4 ld4(const float* w, int s, int yy, int ip) {
    if ((unsigned)yy >= (unsigned)NP) return make_float4(0.f, 0.f, 0.f, 0.f);
    return *(const float4*)(w + 2 * (s * NP2 + yy * NP + 2 * ip));
}
__device__ __forceinline__ float4 shup4(float4 v) {
    return make_float4(__shfl_up(v.x, 1), __shfl_up(v.y, 1),
                       __shfl_up(v.z, 1), __shfl_up(v.w, 1));
}
__device__ __forceinline__ float4 shdn4(float4 v) {
    return make_float4(__shfl_down(v.x, 1), __shfl_down(v.y, 1),
                       __shfl_down(v.z, 1), __shfl_down(v.w, 1));
}

__global__ void detect_mode(const void* vptr) {
    if (threadIdx.x == 0 && blockIdx.x == 0) {
        const __hip_bfloat16* p = (const __hip_bfloat16*)vptr;
        int ok = 1;
        for (int i = 0; i < 32; i += 2) {
            float f = __bfloat162float(p[i]);
            if (!(f >= 1000.f && f <= 3000.f)) ok = 0;
        }
        g_mode = ok;
    }
}

__global__ void zero_state() {
    int i = blockIdx.x * blockDim.x + threadIdx.x;
    if (i >= SNP2 / 2) return;           // each array = 2*SNP2 floats = SNP2/2 float4
    float4 z = make_float4(0.f, 0.f, 0.f, 0.f);
    ((float4*)g_w[0])[i] = z;  ((float4*)g_w[1])[i] = z;
    ((float4*)g_px[0])[i] = z; ((float4*)g_px[1])[i] = z;
    ((float4*)g_py[0])[i] = z; ((float4*)g_py[1])[i] = z;
    ((float4*)g_zx)[i] = z;    ((float4*)g_zy)[i] = z;
}

__global__ void prep_pad(const void* __restrict__ v, const void* __restrict__ sc) {
    int i = blockIdx.x * blockDim.x + threadIdx.x;
    if (i >= NP2) return;
    int y = i / NP, x = i % NP;
    int vy = clampi(y - PAD, 0, NYX - 1);
    int vx = clampi(x - PAD, 0, NYX - 1);
    float vv = in_ld(v, vy * NYX + vx);
    float vd = vv * DT;
    float s = 0.f;
    if (y >= PAD && y < PAD + NYX && x >= PAD && x < PAD + NYX)
        s = in_ld(sc, (y - PAD) * NYX + (x - PAD));
    g_vb[2 * i]     = vd * vd;
    g_vb[2 * i + 1] = 2.f * vv * s * DT * DT;
    if (i < NP) {
        float fi = (float)i;
        float f1 = fminf(fmaxf((22.f - fi) * 0.05f, 0.f), 1.f);
        float f2 = fminf(fmaxf((fi - 421.f) * 0.05f, 0.f), 1.f);
        float frac = fmaxf(f1, f2);
        float sigma = 259.0408229f * frac * frac;
        const float alpha = 78.53981634f;
        float a = expf(-(sigma + alpha) * DT);
        g_pa[i] = a;
        g_pb[i] = (sigma > 0.f) ? sigma / (sigma + alpha) * (a - 1.f) : 0.f;
    }
}

__global__ void prep_src(const void* __restrict__ amp, const int* __restrict__ sloc,
                         const void* __restrict__ v, const void* __restrict__ sc) {
    int i = blockIdx.x * blockDim.x + threadIdx.x;
    if (i >= NT * NS) return;
    int s = i % NS, t = i / NS;
    int ly = clampi(sloc[s * 2 + 0], 0, NYX - 1);
    int lx = clampi(sloc[s * 2 + 1], 0, NYX - 1);
    float a  = in_ld(amp, s * NT + t);
    float vv = in_ld(v,  ly * NYX + lx);
    float ss = in_ld(sc, ly * NYX + lx);
    g_fbg[i] = -a * vv * vv * DT * DT;
    g_fsc[i] = -2.f * a * vv * ss * DT * DT;
    if (i < NS) {
        g_spos[2 * i]     = ly + PAD;
        g_spos[2 * i + 1] = lx + PAD;
    }
}

// Interior-row update (pb[y]==0 guaranteed: no psi_y/zeta_y/dpy).
// All lanes must call (shuffles inside); halo lanes exit after shuffles.
__device__ __forceinline__ void row_interior(
    int t, int s, int y, int ip, bool inb, bool owner, bool pxreg,
    float pbx0, float pbx1, float pax0, float pax1,
    float4 ym2, float4 ym1, float4 w4, float4 yp1, float4 yp2,
    int cur, int nxt)
{
    const int x0 = 2 * ip, x1 = x0 + 1;
    const int yx  = y * NP + x0;
    const int idx = s * NP2 + yx;
    const float4 z4 = make_float4(0.f, 0.f, 0.f, 0.f);

    float4 wl = shup4(w4);         // pair ip-1
    float4 wr = shdn4(w4);         // pair ip+1

    float d2x_b0 = 0.f, d2x_s0 = 0.f, d2x_b1 = 0.f, d2x_s1 = 0.f;
    float4 pxn = z4;
    if (inb) {
        d2x_b0 = (C2A * (wl.x + wr.x) + C2B * (wl.z + w4.z) + C2C * w4.x) * INVH2;
        d2x_s0 = (C2A * (wl.y + wr.y) + C2B * (wl.w + w4.w) + C2C * w4.y) * INVH2;
        d2x_b1 = (C2A * (wl.z + wr.z) + C2B * (w4.x + wr.x) + C2C * w4.z) * INVH2;
        d2x_s1 = (C2A * (wl.w + wr.w) + C2B * (w4.y + wr.y) + C2C * w4.w) * INVH2;
        if (pxreg && pbx0 != 0.f) {      // pb pair-uniform
            float4 pxo = *(const float4*)(g_px[cur] + 2 * idx);
            float dwb0 = (C1A * wl.x - C1B * wl.z + C1B * w4.z - C1A * wr.x) * INVH;
            float dws0 = (C1A * wl.y - C1B * wl.w + C1B * w4.w - C1A * wr.y) * INVH;
            float dwb1 = (C1A * wl.z - C1B * w4.x + C1B * wr.x - C1A * wr.z) * INVH;
            float dws1 = (C1A * wl.w - C1B * w4.y + C1B * wr.y - C1A * wr.w) * INVH;
            pxn.x = pax0 * pxo.x + pbx0 * dwb0;
            pxn.y = pax0 * pxo.y + pbx0 * dws0;
            pxn.z = pax1 * pxo.z + pbx1 * dwb1;
            pxn.w = pax1 * pxo.w + pbx1 * dws1;
            if (owner)
                *(float4*)(g_px[nxt] + 2 * idx) = pxn;
        }
    }

    float dpx_b0 = 0.f, dpx_s0 = 0.f, dpx_b1 = 0.f, dpx_s1 = 0.f;
    {
        float4 pl = shup4(pxn);
        float4 pr = shdn4(pxn);
        if (pxreg) {
            dpx_b0 = (C1A * pl.x - C1B * pl.z + C1B * pxn.z - C1A * pr.x) * INVH;
            dpx_s0 = (C1A * pl.y - C1B * pl.w + C1B * pxn.w - C1A * pr.y) * INVH;
            dpx_b1 = (C1A * pl.z - C1B * pxn.x + C1B * pr.x - C1A * pr.z) * INVH;
            dpx_s1 = (C1A * pl.w - C1B * pxn.y + C1B * pr.y - C1A * pr.w) * INVH;
        }
    }
    if (!owner) return;

    float d2y_b0 = (C2A * (ym2.x + yp2.x) + C2B * (ym1.x + yp1.x) + C2C * w4.x) * INVH2;
    float d2y_s0 = (C2A * (ym2.y + yp2.y) + C2B * (ym1.y + yp1.y) + C2C * w4.y) * INVH2;
    float d2y_b1 = (C2A * (ym2.z + yp2.z) + C2B * (ym1.z + yp1.z) + C2C * w4.z) * INVH2;
    float d2y_s1 = (C2A * (ym2.w + yp2.w) + C2B * (ym1.w + yp1.w) + C2C * w4.w) * INVH2;

    float zx_b0 = 0.f, zx_s0 = 0.f, zx_b1 = 0.f, zx_s1 = 0.f;
    if (pbx0 != 0.f) {
        float4 zo = *(const float4*)(g_zx + 2 * idx);
        zx_b0 = pax0 * zo.x + pbx0 * (d2x_b0 + dpx_b0);
        zx_s0 = pax0 * zo.y + pbx0 * (d2x_s0 + dpx_s0);
        zx_b1 = pax1 * zo.z + pbx1 * (d2x_b1 + dpx_b1);
        zx_s1 = pax1 * zo.w + pbx1 * (d2x_s1 + dpx_s1);
        *(float4*)(g_zx + 2 * idx) = make_float4(zx_b0, zx_s0, zx_b1, zx_s1);
    }

    float4 vb   = *(const float4*)(g_vb + 2 * yx);
    float4 prev = *(const float4*)(g_w[nxt] + 2 * idx);
    float lap_b0 = d2y_b0 + d2x_b0 + dpx_b0 + zx_b0;
    float lap_s0 = d2y_s0 + d2x_s0 + dpx_s0 + zx_s0;
    float lap_b1 = d2y_b1 + d2x_b1 + dpx_b1 + zx_b1;
    float lap_s1 = d2y_s1 + d2x_s1 + dpx_s1 + zx_s1;
    float wn_b0 = vb.x * lap_b0 + 2.f * w4.x - prev.x;
    float wn_s0 = vb.x * lap_s0 + 2.f * w4.y - prev.y + vb.y * lap_b0;
    float wn_b1 = vb.z * lap_b1 + 2.f * w4.z - prev.z;
    float wn_s1 = vb.z * lap_s1 + 2.f * w4.w - prev.w + vb.w * lap_b1;
    if (y == g_spos[2 * s]) {
        int sx = g_spos[2 * s + 1];
        if (sx == x0)      { wn_b0 += g_fbg[t * NS + s]; wn_s0 += g_fsc[t * NS + s]; }
        else if (sx == x1) { wn_b1 += g_fbg[t * NS + s]; wn_s1 += g_fsc[t * NS + s]; }
    }
    *(float4*)(g_w[nxt] + 2 * idx) = make_float4(wn_b0, wn_s0, wn_b1, wn_s1);
}

// one fused timestep. 888 blocks, 256 threads. Block map: xcd = bid&7 owns a
// 222-row half-band of shot s = xcd>>1 (half = xcd&1); k = bid>>3 in [0,111):
//   k < 12  -> FRAME block, rows y0,y0+1; y0 = half ? 420+2k : 2k
//   k >= 12 -> INTERIOR block, rows y0,y0+1; y0 = (half?222:24)+2*(k-12)
// Within a row, R19 layout: wave w lane l -> pair ip = 60w+l-2, owners [2,62).
// Barrier-free, LDS-free; x-exchange via shuffles. bounds(256,4) -> <=128
// VGPR, 4 blocks/CU resident >= 3.47 needed -> one dispatch round.
__global__ void __launch_bounds__(256, 4)
step_fused(int t, const int* __restrict__ rloc, const int* __restrict__ rbloc,
           void* __restrict__ out) {
    const int i = threadIdx.x;
    const int bid = blockIdx.x;
    const int xcd = bid & 7;
    const int s = xcd >> 1;
    const int half = xcd & 1;
    const int k = bid >> 3;
    const int cur = t & 1, nxt = cur ^ 1;
    const bool isframe = (k < 12);
    const int y0 = isframe ? (half ? 420 + 2 * k : 2 * k)
                           : ((half ? 222 : 24) + 2 * (k - 12));

    if (t > 0 && isframe && y0 == 0 && i < 2 * NREC) {   // record step t-1
        int r = i % NREC;
        bool isbg = i < NREC;
        const int* rl = isbg ? rbloc : rloc;
        int ry = clampi(rl[(s * NREC + r) * 2 + 0], 0, NYX - 1) + PAD;
        int rx = clampi(rl[(s * NREC + r) * 2 + 1], 0, NYX - 1) + PAD;
        float val = g_w[cur][2 * (s * NP2 + ry * NP + rx) + (isbg ? 0 : 1)];
        int base = isbg ? (2 * SNP2) : (2 * SNP2 + NS * NREC * NT);
        out_st(out, base + (s * NREC + r) * NT + (t - 1), val);
    }

    const int wid  = i >> 6;
    const int lane = i & 63;
    const int ip   = 60 * wid + lane - 2;              // pair index
    const bool inb   = (unsigned)ip < 222u;
    const bool owner = (lane >= 2) && (lane < 62) && inb;

    const int x0 = 2 * ip, x1 = x0 + 1;
    const float4 z4 = make_float4(0.f, 0.f, 0.f, 0.f);
    const float* wc = g_w[cur];

    float pbx0 = 0.f, pbx1 = 0.f, pax0 = 0.f, pax1 = 0.f;
    if (inb) {
        pbx0 = g_pb[x0]; pbx1 = g_pb[x1];
        pax0 = g_pa[x0]; pax1 = g_pa[x1];
    }
    const bool pxreg = (ip <= 11 || ip >= 210);

    if (!isframe) {
        // ---- interior: 2 rows per thread, 6 shared w-row loads (R23) ----
        const int idx0 = s * NP2 + y0 * NP + x0;
        float4 wm2 = z4, wm1 = z4, wa = z4, wb = z4, wp1 = z4, wp2 = z4;
        if (inb) {
            wm2 = *(const float4*)(wc + 2 * (idx0 - 2 * NP));
            wm1 = *(const float4*)(wc + 2 * (idx0 - NP));
            wa  = *(const float4*)(wc + 2 * idx0);
            wb  = *(const float4*)(wc + 2 * (idx0 + NP));
            wp1 = *(const float4*)(wc + 2 * (idx0 + 2 * NP));
            wp2 = *(const float4*)(wc + 2 * (idx0 + 3 * NP));
        }
        row_interior(t, s, y0,     ip, inb, owner, pxreg, pbx0, pbx1, pax0, pax1,
                     wm2, wm1, wa, wb, wp1, cur, nxt);
        row_interior(t, s, y0 + 1, ip, inb, owner, pxreg, pbx0, pbx1, pax0, pax1,
                     wm1, wa, wb, wp1, wp2, cur, nxt);
        return;
    }

    // ---- frame: 2 rows y0 (A), y0+1 (B); shared wy[10] window ----
    const int yA = y0, yB = y0 + 1;
    const int idxA = s * NP2 + yA * NP + x0;
    const int idxB = idxA + NP;

    float4 w4A = z4, w4B = z4;
    if (inb) {
        w4A = *(const float4*)(wc + 2 * idxA);
        w4B = *(const float4*)(wc + 2 * idxB);
    }

    // x stencils + psi_x for both rows (shuffles: all lanes participate)
    float4 wlA = shup4(w4A), wrA = shdn4(w4A);
    float4 wlB = shup4(w4B), wrB = shdn4(w4B);

    float d2xA_b0 = 0.f, d2xA_s0 = 0.f, d2xA_b1 = 0.f, d2xA_s1 = 0.f;
    float d2xB_b0 = 0.f, d2xB_s0 = 0.f, d2xB_b1 = 0.f, d2xB_s1 = 0.f;
    float4 pxnA = z4, pxnB = z4;
    if (inb) {
        d2xA_b0 = (C2A * (wlA.x + wrA.x) + C2B * (wlA.z + w4A.z) + C2C * w4A.x) * INVH2;
        d2xA_s0 = (C2A * (wlA.y + wrA.y) + C2B * (wlA.w + w4A.w) + C2C * w4A.y) * INVH2;
        d2xA_b1 = (C2A * (wlA.z + wrA.z) + C2B * (w4A.x + wrA.x) + C2C * w4A.z) * INVH2;
        d2xA_s1 = (C2A * (wlA.w + wrA.w) + C2B * (w4A.y + wrA.y) + C2C * w4A.w) * INVH2;
        d2xB_b0 = (C2A * (wlB.x + wrB.x) + C2B * (wlB.z + w4B.z) + C2C * w4B.x) * INVH2;
        d2xB_s0 = (C2A * (wlB.y + wrB.y) + C2B * (wlB.w + w4B.w) + C2C * w4B.y) * INVH2;
        d2xB_b1 = (C2A * (wlB.z + wrB.z) + C2B * (w4B.x + wrB.x) + C2C * w4B.z) * INVH2;
        d2xB_s1 = (C2A * (wlB.w + wrB.w) + C2B * (w4B.y + wrB.y) + C2C * w4B.w) * INVH2;
        if (pxreg && pbx0 != 0.f) {
            float4 pxoA = *(const float4*)(g_px[cur] + 2 * idxA);
            float4 pxoB = *(const float4*)(g_px[cur] + 2 * idxB);
            float dwb0 = (C1A * wlA.x - C1B * wlA.z + C1B * w4A.z - C1A * wrA.x) * INVH;
            float dws0 = (C1A * wlA.y - C1B * wlA.w + C1B * w4A.w - C1A * wrA.y) * INVH;
            float dwb1 = (C1A * wlA.z - C1B * w4A.x + C1B * wrA.x - C1A * wrA.z) * INVH;
            float dws1 = (C1A * wlA.w - C1B * w4A.y + C1B * wrA.y - C1A * wrA.w) * INVH;
            pxnA.x = pax0 * pxoA.x + pbx0 * dwb0;
            pxnA.y = pax0 * pxoA.y + pbx0 * dws0;
            pxnA.z = pax1 * pxoA.z + pbx1 * dwb1;
            pxnA.w = pax1 * pxoA.w + pbx1 * dws1;
            dwb0 = (C1A * wlB.x - C1B * wlB.z + C1B * w4B.z - C1A * wrB.x) * INVH;
            dws0 = (C1A * wlB.y - C1B * wlB.w + C1B * w4B.w - C1A * wrB.y) * INVH;
            dwb1 = (C1A * wlB.z - C1B * w4B.x + C1B * wrB.x - C1A * wrB.z) * INVH;
            dws1 = (C1A * wlB.w - C1B * w4B.y + C1B * wrB.y - C1A * wrB.w) * INVH;
            pxnB.x = pax0 * pxoB.x + pbx0 * dwb0;
            pxnB.y = pax0 * pxoB.y + pbx0 * dws0;
            pxnB.z = pax1 * pxoB.z + pbx1 * dwb1;
            pxnB.w = pax1 * pxoB.w + pbx1 * dws1;
            if (owner) {
                *(float4*)(g_px[nxt] + 2 * idxA) = pxnA;
                *(float4*)(g_px[nxt] + 2 * idxB) = pxnB;
            }
        }
    }

    float dpxA_b0 = 0.f, dpxA_s0 = 0.f, dpxA_b1 = 0.f, dpxA_s1 = 0.f;
    float dpxB_b0 = 0.f, dpxB_s0 = 0.f, dpxB_b1 = 0.f, dpxB_s1 = 0.f;
    {
        float4 plA = shup4(pxnA), prA = shdn4(pxnA);
        float4 plB = shup4(pxnB), prB = shdn4(pxnB);
        if (pxreg) {
            dpxA_b0 = (C1A * plA.x - C1B * plA.z + C1B * pxnA.z - C1A * prA.x) * INVH;
            dpxA_s0 = (C1A * plA.y - C1B * plA.w + C1B * pxnA.w - C1A * prA.y) * INVH;
            dpxA_b1 = (C1A * plA.z - C1B * pxnA.x + C1B * prA.x - C1A * prA.z) * INVH;
            dpxA_s1 = (C1A * plA.w - C1B * pxnA.y + C1B * prA.y - C1A * prA.w) * INVH;
            dpxB_b0 = (C1A * plB.x - C1B * plB.z + C1B * pxnB.z - C1A * prB.x) * INVH;
            dpxB_s0 = (C1A * plB.y - C1B * plB.w + C1B * pxnB.w - C1A * prB.y) * INVH;
            dpxB_b1 = (C1A * plB.z - C1B * pxnB.x + C1B * prB.x - C1A * prB.z) * INVH;
            dpxB_s1 = (C1A * plB.w - C1B * pxnB.y + C1B * prB.y - C1A * prB.w) * INVH;
        }
    }
    if (!owner) return;

    // shared w window: wy[kk] = row y0-4+kk, kk=0..9 (wy[4]=A, wy[5]=B)
    float4 wy[10];
    wy[4] = w4A; wy[5] = w4B;
    #pragma unroll
    for (int kk = 0; kk < 10; ++kk) {
        if (kk == 4 || kk == 5) continue;
        wy[kk] = ld4(wc, s, y0 - 4 + kk, ip);
    }
    float d2yA_b0 = (C2A * (wy[2].x + wy[6].x) + C2B * (wy[3].x + wy[5].x) + C2C * wy[4].x) * INVH2;
    float d2yA_s0 = (C2A * (wy[2].y + wy[6].y) + C2B * (wy[3].y + wy[5].y) + C2C * wy[4].y) * INVH2;
    float d2yA_b1 = (C2A * (wy[2].z + wy[6].z) + C2B * (wy[3].z + wy[5].z) + C2C * wy[4].z) * INVH2;
    float d2yA_s1 = (C2A * (wy[2].w + wy[6].w) + C2B * (wy[3].w + wy[5].w) + C2C * wy[4].w) * INVH2;
    float d2yB_b0 = (C2A * (wy[3].x + wy[7].x) + C2B * (wy[4].x + wy[6].x) + C2C * wy[5].x) * INVH2;
    float d2yB_s0 = (C2A * (wy[3].y + wy[7].y) + C2B * (wy[4].y + wy[6].y) + C2C * wy[5].y) * INVH2;
    float d2yB_b1 = (C2A * (wy[3].z + wy[7].z) + C2B * (wy[4].z + wy[6].z) + C2C * wy[5].z) * INVH2;
    float d2yB_s1 = (C2A * (wy[3].w + wy[7].w) + C2B * (wy[4].w + wy[6].w) + C2C * wy[5].w) * INVH2;

    // pn[m] = psi_y_new at row y0-2+m, m=0..5 (C1 stencil: wy[m],[m+1],[m+3],[m+4])
    float4 pn[6];
    #pragma unroll
    for (int m = 0; m < 6; ++m) {
        int yy = y0 - 2 + m;
        float pbv = ((unsigned)yy < (unsigned)NP) ? g_pb[yy] : 0.f;  // uniform
        float4 r = z4;
        if (pbv != 0.f) {
            float pav = g_pa[yy];
            float4 po = *(const float4*)(g_py[cur] + 2 * (s * NP2 + yy * NP + x0));
            float db0 = (C1A * wy[m].x - C1B * wy[m+1].x + C1B * wy[m+3].x - C1A * wy[m+4].x) * INVH;
            float ds0 = (C1A * wy[m].y - C1B * wy[m+1].y + C1B * wy[m+3].y - C1A * wy[m+4].y) * INVH;
            float db1 = (C1A * wy[m].z - C1B * wy[m+1].z + C1B * wy[m+3].z - C1A * wy[m+4].z) * INVH;
            float ds1 = (C1A * wy[m].w - C1B * wy[m+1].w + C1B * wy[m+3].w - C1A * wy[m+4].w) * INVH;
            r.x = pav * po.x + pbv * db0;  r.y = pav * po.y + pbv * ds0;
            r.z = pav * po.z + pbv * db1;  r.w = pav * po.w + pbv * ds1;
        }
        pn[m] = r;
    }
    float dpyA_b0 = (C1A * pn[0].x - C1B * pn[1].x + C1B * pn[3].x - C1A * pn[4].x) * INVH;
    float dpyA_s0 = (C1A * pn[0].y - C1B * pn[1].y + C1B * pn[3].y - C1A * pn[4].y) * INVH;
    float dpyA_b1 = (C1A * pn[0].z - C1B * pn[1].z + C1B * pn[3].z - C1A * pn[4].z) * INVH;
    float dpyA_s1 = (C1A * pn[0].w - C1B * pn[1].w + C1B * pn[3].w - C1A * pn[4].w) * INVH;
    float dpyB_b0 = (C1A * pn[1].x - C1B * pn[2].x + C1B * pn[4].x - C1A * pn[5].x) * INVH;
    float dpyB_s0 = (C1A * pn[1].y - C1B * pn[2].y + C1B * pn[4].y - C1A * pn[5].y) * INVH;
    float dpyB_b1 = (C1A * pn[1].z - C1B * pn[2].z + C1B * pn[4].z - C1A * pn[5].z) * INVH;
    float dpyB_s1 = (C1A * pn[1].w - C1B * pn[2].w + C1B * pn[4].w - C1A * pn[5].w) * INVH;

    const float pbyA = g_pb[yA], pbyB = g_pb[yB];
    if (pbyA != 0.f) *(float4*)(g_py[nxt] + 2 * idxA) = pn[2];
    if (pbyB != 0.f) *(float4*)(g_py[nxt] + 2 * idxB) = pn[3];

    // zeta_y per row
    float zyA_b0 = 0.f, zyA_s0 = 0.f, zyA_b1 = 0.f, zyA_s1 = 0.f;
    float zyB_b0 = 0.f, zyB_s0 = 0.f, zyB_b1 = 0.f, zyB_s1 = 0.f;
    if (pbyA != 0.f) {
        float pay = g_pa[yA];
        float4 zo = *(const float4*)(g_zy + 2 * idxA);
        zyA_b0 = pay * zo.x + pbyA * (d2yA_b0 + dpyA_b0);
        zyA_s0 = pay * zo.y + pbyA * (d2yA_s0 + dpyA_s0);
        zyA_b1 = pay * zo.z + pbyA * (d2yA_b1 + dpyA_b1);
        zyA_s1 = pay * zo.w + pbyA * (d2yA_s1 + dpyA_s1);
        *(float4*)(g_zy + 2 * idxA) = make_float4(zyA_b0, zyA_s0, zyA_b1, zyA_s1);
    }
    if (pbyB != 0.f) {
        float pay = g_pa[yB];
        float4 zo = *(const float4*)(g_zy + 2 * idxB);
        zyB_b0 = pay * zo.x + pbyB * (d2yB_b0 + dpyB_b0);
        zyB_s0 = pay * zo.y + pbyB * (d2yB_s0 + dpyB_s0);
        zyB_b1 = pay * zo.z + pbyB * (d2yB_b1 + dpyB_b1);
        zyB_s1 = pay * zo.w + pbyB * (d2yB_s1 + dpyB_s1);
        *(float4*)(g_zy + 2 * idxB) = make_float4(zyB_b0, zyB_s0, zyB_b1, zyB_s1);
    }

    // zeta_x per row (pbx pair-uniform; pbx!=0 implies pxreg)
    float zxA_b0 = 0.f, zxA_s0 = 0.f, zxA_b1 = 0.f, zxA_s1 = 0.f;
    float zxB_b0 = 0.f, zxB_s0 = 0.f, zxB_b1 = 0.f, zxB_s1 = 0.f;
    if (pbx0 != 0.f) {
        float4 zoA = *(const float4*)(g_zx + 2 * idxA);
        float4 zoB = *(const float4*)(g_zx + 2 * idxB);
        zxA_b0 = pax0 * zoA.x + pbx0 * (d2xA_b0 + dpxA_b0);
        zxA_s0 = pax0 * zoA.y + pbx0 * (d2xA_s0 + dpxA_s0);
        zxA_b1 = pax1 * zoA.z + pbx1 * (d2xA_b1 + dpxA_b1);
        zxA_s1 = pax1 * zoA.w + pbx1 * (d2xA_s1 + dpxA_s1);
        *(float4*)(g_zx + 2 * idxA) = make_float4(zxA_b0, zxA_s0, zxA_b1, zxA_s1);
        zxB_b0 = pax0 * zoB.x + pbx0 * (d2xB_b0 + dpxB_b0);
        zxB_s0 = pax0 * zoB.y + pbx0 * (d2xB_s0 + dpxB_s0);
        zxB_b1 = pax1 * zoB.z + pbx1 * (d2xB_b1 + dpxB_b1);
        zxB_s1 = pax1 * zoB.w + pbx1 * (d2xB_s1 + dpxB_s1);
        *(float4*)(g_zx + 2 * idxB) = make_float4(zxB_b0, zxB_s0, zxB_b1, zxB_s1);
    }

    // final update per row
    {
        float4 vb   = *(const float4*)(g_vb + 2 * (yA * NP + x0));
        float4 prev = *(const float4*)(g_w[nxt] + 2 * idxA);
        float lap_b0 = d2yA_b0 + d2xA_b0 + dpyA_b0 + dpxA_b0 + zyA_b0 + zxA_b0;
        float lap_s0 = d2yA_s0 + d2xA_s0 + dpyA_s0 + dpxA_s0 + zyA_s0 + zxA_s0;
        float lap_b1 = d2yA_b1 + d2xA_b1 + dpyA_b1 + dpxA_b1 + zyA_b1 + zxA_b1;
        float lap_s1 = d2yA_s1 + d2xA_s1 + dpyA_s1 + dpxA_s1 + zyA_s1 + zxA_s1;
        float wn_b0 = vb.x * lap_b0 + 2.f * w4A.x - prev.x;
        float wn_s0 = vb.x * lap_s0 + 2.f * w4A.y - prev.y + vb.y * lap_b0;
        float wn_b1 = vb.z * lap_b1 + 2.f * w4A.z - prev.z;
        float wn_s1 = vb.z * lap_s1 + 2.f * w4A.w - prev.w + vb.w * lap_b1;
        if (yA == g_spos[2 * s]) {
            int sx = g_spos[2 * s + 1];
            if (sx == x0)      { wn_b0 += g_fbg[t * NS + s]; wn_s0 += g_fsc[t * NS + s]; }
            else if (sx == x1) { wn_b1 += g_fbg[t * NS + s]; wn_s1 += g_fsc[t * NS + s]; }
        }
        *(float4*)(g_w[nxt] + 2 * idxA) = make_float4(wn_b0, wn_s0, wn_b1, wn_s1);
    }
    {
        float4 vb   = *(const float4*)(g_vb + 2 * (yB * NP + x0));
        float4 prev = *(const float4*)(g_w[nxt] + 2 * idxB);
        float lap_b0 = d2yB_b0 + d2xB_b0 + dpyB_b0 + dpxB_b0 + zyB_b0 + zxB_b0;
        float lap_s0 = d2yB_s0 + d2xB_s0 + dpyB_s0 + dpxB_s0 + zyB_s0 + zxB_s0;
        float lap_b1 = d2yB_b1 + d2xB_b1 + dpyB_b1 + dpxB_b1 + zyB_b1 + zxB_b1;
        float lap_s1 = d2yB_s1 + d2xB_s1 + dpyB_s1 + dpxB_s1 + zyB_s1 + zxB_s1;
        float wn_b0 = vb.x * lap_b0 + 2.f * w4B.x - prev.x;
        float wn_s0 = vb.x * lap_s0 + 2.f * w4B.y - prev.y + vb.y * lap_b0;
        float wn_b1 = vb.z * lap_b1 + 2.f * w4B.z - prev.z;
        float wn_s1 = vb.z * lap_s1 + 2.f * w4B.w - prev.w + vb.w * lap_b1;
        if (yB == g_spos[2 * s]) {
            int sx = g_spos[2 * s + 1];
            if (sx == x0)      { wn_b0 += g_fbg[t * NS + s]; wn_s0 += g_fsc[t * NS + s]; }
            else if (sx == x1) { wn_b1 += g_fbg[t * NS + s]; wn_s1 += g_fsc[t * NS + s]; }
        }
        *(float4*)(g_w[nxt] + 2 * idxB) = make_float4(wn_b0, wn_s0, wn_b1, wn_s1);
    }
}

__global__ void finalize(const int* __restrict__ rloc, const int* __restrict__ rbloc,
                         void* __restrict__ out) {
    int i = blockIdx.x * blockDim.x + threadIdx.x;
    const float* w0 = g_w[0];     // NT even: newest field in buffer 0
    if (i < SNP2) {
        out_st(out, i,        w0[2 * i]);       // bg flat
        out_st(out, SNP2 + i, w0[2 * i + 1]);   // scattered flat
    }
    if (i < 2 * NS * NREC) {      // record last step (t = NT-1)
        bool isbg = i < NS * NREC;
        int k = isbg ? i : i - NS * NREC;
        int s = k / NREC, r = k % NREC;
        const int* rl = isbg ? rbloc : rloc;
        int ry = clampi(rl[(s * NREC + r) * 2 + 0], 0, NYX - 1) + PAD;
        int rx = clampi(rl[(s * NREC + r) * 2 + 1], 0, NYX - 1) + PAD;
        float val = w0[2 * (s * NP2 + ry * NP + rx) + (isbg ? 0 : 1)];
        int base = isbg ? (2 * SNP2) : (2 * SNP2 + NS * NREC * NT);
        out_st(out, base + (s * NREC + r) * NT + (NT - 1), val);
    }
}

extern "C" void kernel_launch(void* const* d_in, const int* in_sizes, int n_in,
                              void* d_out, int out_size, void* d_ws, size_t ws_size,
                              hipStream_t stream) {
    const void* v   = d_in[0];
    const void* sc  = d_in[1];
    const void* amp = d_in[2];
    const int* sloc  = (const int*)d_in[3];
    const int* rloc  = (const int*)d_in[4];
    const int* rbloc = (const int*)d_in[5];

    detect_mode<<<1, 64, 0, stream>>>(v);
    zero_state<<<(SNP2 / 2 + 255) / 256, 256, 0, stream>>>();
    prep_pad<<<(NP2 + 255) / 256, 256, 0, stream>>>(v, sc);
    prep_src<<<(NT * NS + 255) / 256, 256, 0, stream>>>(amp, sloc, v, sc);

    for (int t = 0; t < NT; ++t)
        step_fused<<<NBLK, 256, 0, stream>>>(t, rloc, rbloc, d_out);

    finalize<<<(SNP2 + 255) / 256, 256, 0, stream>>>(rloc, rbloc, d_out);
}

// Round 11
// 2078.554 us; speedup vs baseline: 1.1108x; 1.1108x over previous
//
#include <hip/hip_runtime.h>
#include <hip/hip_bf16.h>

// ScalarBorn: 4th-order FD scalar wave + Born scattering with CPML, MI355X.
// R25 = R23 (2115us best; R24 frame-merge REVERTED +9% -- frame register fat
// leaked into the interior majority's cap) + INTERIOR 3-ROW BLOCKS: thread
// owns rows y0..y0+2, shared 7-row w window (2.33 loads/row vs 3.0; interior
// loads/row 4.33 vs 5.0 float4, -13%). Frame path + (256,5) envelope are
// byte-identical to R23. Grid 720 blocks (8 x (24 frame + 66 int3)), all
// resident. Discriminating probe: win => L2-BW-sensitive; neutral => bound
// by unique LLC bytes + launch overhead (declare floor next).
// Kept: XCD banding (R15 -33%), one-round (R18), shuffle x-exchange / no LDS
// / no barriers (R19), interior row-merge traffic cut (R23 -9%).
// Falsified: 2-row frame merge (R24 +9%), 512-thr 2-row cap64 (R22 +19%),
// direct-load x-exch (R21 +54%), declustering (R20 +5%), full hoist (R16
// +19%), cheap hoist (R17 +5%), aggregation (R8/R10), barrier removal w/
// LDS (R12/R13), load cuts (R7), grid.sync (R4).

constexpr int NYX  = 400;
constexpr int NS   = 4;
constexpr int NREC = 100;
constexpr int NT   = 300;
constexpr int PAD  = 22;
constexpr int NP   = 444;
constexpr int NP2  = NP * NP;          // 197136
constexpr int SNP2 = NS * NP2;         // 788544
constexpr int NBLK = 720;              // 8 half-bands x (24 frame + 66 int3)
constexpr float DT    = 0.0005f;
constexpr float INVH  = 0.2f;
constexpr float INVH2 = 0.04f;
constexpr float C1A = 1.0f / 12.0f;
constexpr float C1B = 2.0f / 3.0f;
constexpr float C2A = -1.0f / 12.0f;
constexpr float C2B = 4.0f / 3.0f;
constexpr float C2C = -2.5f;

// interleaved state: element (b,s) pair for grid index idx lives at [2*idx, 2*idx+1]
__device__ __align__(16) float g_w[2][2 * SNP2];   // wavefield ping-pong
__device__ __align__(16) float g_px[2][2 * SNP2];  // psi_x dbuf
__device__ __align__(16) float g_py[2][2 * SNP2];  // psi_y dbuf
__device__ __align__(16) float g_zx[2 * SNP2];     // zeta_x
__device__ __align__(16) float g_zy[2 * SNP2];     // zeta_y
__device__ __align__(16) float g_vb[2 * NP2];      // (v2dt2, bscale) pairs
__device__ float g_pa[NP];
__device__ float g_pb[NP];
__device__ float g_fbg[NT * NS];
__device__ float g_fsc[NT * NS];
__device__ int   g_spos[2 * NS];
__device__ int   g_mode;               // 1 = bf16 io, 0 = f32 io

__device__ __forceinline__ int clampi(int v, int lo, int hi) {
    return v < lo ? lo : (v > hi ? hi : v);
}
__device__ __forceinline__ float in_ld(const void* p, int i) {
    if (g_mode) return __bfloat162float(((const __hip_bfloat16*)p)[i]);
    return ((const float*)p)[i];
}
__device__ __forceinline__ void out_st(void* p, int i, float v) {
    if (g_mode) ((__hip_bfloat16*)p)[i] = __float2bfloat16(v);
    else        ((float*)p)[i] = v;
}
// float4 = (b0,s0,b1,s1) at row yy, col pair ip of shot s; 0 if row OOB
__device__ __forceinline__ float4 ld4(const float* w, int s, int yy, int ip) {
    if ((unsigned)yy >= (unsigned)NP) return make_float4(0.f, 0.f, 0.f, 0.f);
    return *(const float4*)(w + 2 * (s * NP2 + yy * NP + 2 * ip));
}
__device__ __forceinline__ float4 shup4(float4 v) {
    return make_float4(__shfl_up(v.x, 1), __shfl_up(v.y, 1),
                       __shfl_up(v.z, 1), __shfl_up(v.w, 1));
}
__device__ __forceinline__ float4 shdn4(float4 v) {
    return make_float4(__shfl_down(v.x, 1), __shfl_down(v.y, 1),
                       __shfl_down(v.z, 1), __shfl_down(v.w, 1));
}

__global__ void detect_mode(const void* vptr) {
    if (threadIdx.x == 0 && blockIdx.x == 0) {
        const __hip_bfloat16* p = (const __hip_bfloat16*)vptr;
        int ok = 1;
        for (int i = 0; i < 32; i += 2) {
            float f = __bfloat162float(p[i]);
            if (!(f >= 1000.f && f <= 3000.f)) ok = 0;
        }
        g_mode = ok;
    }
}

__global__ void zero_state() {
    int i = blockIdx.x * blockDim.x + threadIdx.x;
    if (i >= SNP2 / 2) return;           // each array = 2*SNP2 floats = SNP2/2 float4
    float4 z = make_float4(0.f, 0.f, 0.f, 0.f);
    ((float4*)g_w[0])[i] = z;  ((float4*)g_w[1])[i] = z;
    ((float4*)g_px[0])[i] = z; ((float4*)g_px[1])[i] = z;
    ((float4*)g_py[0])[i] = z; ((float4*)g_py[1])[i] = z;
    ((float4*)g_zx)[i] = z;    ((float4*)g_zy)[i] = z;
}

__global__ void prep_pad(const void* __restrict__ v, const void* __restrict__ sc) {
    int i = blockIdx.x * blockDim.x + threadIdx.x;
    if (i >= NP2) return;
    int y = i / NP, x = i % NP;
    int vy = clampi(y - PAD, 0, NYX - 1);
    int vx = clampi(x - PAD, 0, NYX - 1);
    float vv = in_ld(v, vy * NYX + vx);
    float vd = vv * DT;
    float s = 0.f;
    if (y >= PAD && y < PAD + NYX && x >= PAD && x < PAD + NYX)
        s = in_ld(sc, (y - PAD) * NYX + (x - PAD));
    g_vb[2 * i]     = vd * vd;
    g_vb[2 * i + 1] = 2.f * vv * s * DT * DT;
    if (i < NP) {
        float fi = (float)i;
        float f1 = fminf(fmaxf((22.f - fi) * 0.05f, 0.f), 1.f);
        float f2 = fminf(fmaxf((fi - 421.f) * 0.05f, 0.f), 1.f);
        float frac = fmaxf(f1, f2);
        float sigma = 259.0408229f * frac * frac;
        const float alpha = 78.53981634f;
        float a = expf(-(sigma + alpha) * DT);
        g_pa[i] = a;
        g_pb[i] = (sigma > 0.f) ? sigma / (sigma + alpha) * (a - 1.f) : 0.f;
    }
}

__global__ void prep_src(const void* __restrict__ amp, const int* __restrict__ sloc,
                         const void* __restrict__ v, const void* __restrict__ sc) {
    int i = blockIdx.x * blockDim.x + threadIdx.x;
    if (i >= NT * NS) return;
    int s = i % NS, t = i / NS;
    int ly = clampi(sloc[s * 2 + 0], 0, NYX - 1);
    int lx = clampi(sloc[s * 2 + 1], 0, NYX - 1);
    float a  = in_ld(amp, s * NT + t);
    float vv = in_ld(v,  ly * NYX + lx);
    float ss = in_ld(sc, ly * NYX + lx);
    g_fbg[i] = -a * vv * vv * DT * DT;
    g_fsc[i] = -2.f * a * vv * ss * DT * DT;
    if (i < NS) {
        g_spos[2 * i]     = ly + PAD;
        g_spos[2 * i + 1] = lx + PAD;
    }
}

// Interior-row update (pb[y]==0 guaranteed: no psi_y/zeta_y/dpy).
// All lanes must call (shuffles inside); halo lanes exit after shuffles.
__device__ __forceinline__ void row_interior(
    int t, int s, int y, int ip, bool inb, bool owner, bool pxreg,
    float pbx0, float pbx1, float pax0, float pax1,
    float4 ym2, float4 ym1, float4 w4, float4 yp1, float4 yp2,
    int cur, int nxt)
{
    const int x0 = 2 * ip, x1 = x0 + 1;
    const int yx  = y * NP + x0;
    const int idx = s * NP2 + yx;
    const float4 z4 = make_float4(0.f, 0.f, 0.f, 0.f);

    float4 wl = shup4(w4);         // pair ip-1
    float4 wr = shdn4(w4);         // pair ip+1

    float d2x_b0 = 0.f, d2x_s0 = 0.f, d2x_b1 = 0.f, d2x_s1 = 0.f;
    float4 pxn = z4;
    if (inb) {
        d2x_b0 = (C2A * (wl.x + wr.x) + C2B * (wl.z + w4.z) + C2C * w4.x) * INVH2;
        d2x_s0 = (C2A * (wl.y + wr.y) + C2B * (wl.w + w4.w) + C2C * w4.y) * INVH2;
        d2x_b1 = (C2A * (wl.z + wr.z) + C2B * (w4.x + wr.x) + C2C * w4.z) * INVH2;
        d2x_s1 = (C2A * (wl.w + wr.w) + C2B * (w4.y + wr.y) + C2C * w4.w) * INVH2;
        if (pxreg && pbx0 != 0.f) {      // pb pair-uniform
            float4 pxo = *(const float4*)(g_px[cur] + 2 * idx);
            float dwb0 = (C1A * wl.x - C1B * wl.z + C1B * w4.z - C1A * wr.x) * INVH;
            float dws0 = (C1A * wl.y - C1B * wl.w + C1B * w4.w - C1A * wr.y) * INVH;
            float dwb1 = (C1A * wl.z - C1B * w4.x + C1B * wr.x - C1A * wr.z) * INVH;
            float dws1 = (C1A * wl.w - C1B * w4.y + C1B * wr.y - C1A * wr.w) * INVH;
            pxn.x = pax0 * pxo.x + pbx0 * dwb0;
            pxn.y = pax0 * pxo.y + pbx0 * dws0;
            pxn.z = pax1 * pxo.z + pbx1 * dwb1;
            pxn.w = pax1 * pxo.w + pbx1 * dws1;
            if (owner)
                *(float4*)(g_px[nxt] + 2 * idx) = pxn;
        }
    }

    float dpx_b0 = 0.f, dpx_s0 = 0.f, dpx_b1 = 0.f, dpx_s1 = 0.f;
    {
        float4 pl = shup4(pxn);
        float4 pr = shdn4(pxn);
        if (pxreg) {
            dpx_b0 = (C1A * pl.x - C1B * pl.z + C1B * pxn.z - C1A * pr.x) * INVH;
            dpx_s0 = (C1A * pl.y - C1B * pl.w + C1B * pxn.w - C1A * pr.y) * INVH;
            dpx_b1 = (C1A * pl.z - C1B * pxn.x + C1B * pr.x - C1A * pr.z) * INVH;
            dpx_s1 = (C1A * pl.w - C1B * pxn.y + C1B * pr.y - C1A * pr.w) * INVH;
        }
    }
    if (!owner) return;

    float d2y_b0 = (C2A * (ym2.x + yp2.x) + C2B * (ym1.x + yp1.x) + C2C * w4.x) * INVH2;
    float d2y_s0 = (C2A * (ym2.y + yp2.y) + C2B * (ym1.y + yp1.y) + C2C * w4.y) * INVH2;
    float d2y_b1 = (C2A * (ym2.z + yp2.z) + C2B * (ym1.z + yp1.z) + C2C * w4.z) * INVH2;
    float d2y_s1 = (C2A * (ym2.w + yp2.w) + C2B * (ym1.w + yp1.w) + C2C * w4.w) * INVH2;

    float zx_b0 = 0.f, zx_s0 = 0.f, zx_b1 = 0.f, zx_s1 = 0.f;
    if (pbx0 != 0.f) {
        float4 zo = *(const float4*)(g_zx + 2 * idx);
        zx_b0 = pax0 * zo.x + pbx0 * (d2x_b0 + dpx_b0);
        zx_s0 = pax0 * zo.y + pbx0 * (d2x_s0 + dpx_s0);
        zx_b1 = pax1 * zo.z + pbx1 * (d2x_b1 + dpx_b1);
        zx_s1 = pax1 * zo.w + pbx1 * (d2x_s1 + dpx_s1);
        *(float4*)(g_zx + 2 * idx) = make_float4(zx_b0, zx_s0, zx_b1, zx_s1);
    }

    float4 vb   = *(const float4*)(g_vb + 2 * yx);
    float4 prev = *(const float4*)(g_w[nxt] + 2 * idx);
    float lap_b0 = d2y_b0 + d2x_b0 + dpx_b0 + zx_b0;
    float lap_s0 = d2y_s0 + d2x_s0 + dpx_s0 + zx_s0;
    float lap_b1 = d2y_b1 + d2x_b1 + dpx_b1 + zx_b1;
    float lap_s1 = d2y_s1 + d2x_s1 + dpx_s1 + zx_s1;
    float wn_b0 = vb.x * lap_b0 + 2.f * w4.x - prev.x;
    float wn_s0 = vb.x * lap_s0 + 2.f * w4.y - prev.y + vb.y * lap_b0;
    float wn_b1 = vb.z * lap_b1 + 2.f * w4.z - prev.z;
    float wn_s1 = vb.z * lap_s1 + 2.f * w4.w - prev.w + vb.w * lap_b1;
    if (y == g_spos[2 * s]) {
        int sx = g_spos[2 * s + 1];
        if (sx == x0)      { wn_b0 += g_fbg[t * NS + s]; wn_s0 += g_fsc[t * NS + s]; }
        else if (sx == x1) { wn_b1 += g_fbg[t * NS + s]; wn_s1 += g_fsc[t * NS + s]; }
    }
    *(float4*)(g_w[nxt] + 2 * idx) = make_float4(wn_b0, wn_s0, wn_b1, wn_s1);
}

// one fused timestep. 720 blocks, 256 threads. Block map: xcd = bid&7 owns a
// 222-row half-band of shot s = xcd>>1 (half = xcd&1); k = bid>>3 in [0,90):
//   k < 24  -> FRAME block, one row y = half ? 420+k : k      (R23/R19 body)
//   k >= 24 -> INTERIOR block, rows y0..y0+2; y0 = (half?222:24)+3*(k-24)
// Within a row, R19 layout: wave w lane l -> pair ip = 60w+l-2, owners [2,62).
// Barrier-free, LDS-free; x-exchange via shuffles. bounds(256,5) -> <=102
// VGPR (R23 envelope), all 720 blocks resident -> one dispatch round.
__global__ void __launch_bounds__(256, 5)
step_fused(int t, const int* __restrict__ rloc, const int* __restrict__ rbloc,
           void* __restrict__ out) {
    const int i = threadIdx.x;
    const int bid = blockIdx.x;
    const int xcd = bid & 7;
    const int s = xcd >> 1;
    const int half = xcd & 1;
    const int k = bid >> 3;
    const int cur = t & 1, nxt = cur ^ 1;
    const bool isframe = (k < 24);
    const int y0 = isframe ? (half ? 420 + k : k)
                           : ((half ? 222 : 24) + 3 * (k - 24));

    if (t > 0 && isframe && y0 == 0 && i < 2 * NREC) {   // record step t-1
        int r = i % NREC;
        bool isbg = i < NREC;
        const int* rl = isbg ? rbloc : rloc;
        int ry = clampi(rl[(s * NREC + r) * 2 + 0], 0, NYX - 1) + PAD;
        int rx = clampi(rl[(s * NREC + r) * 2 + 1], 0, NYX - 1) + PAD;
        float val = g_w[cur][2 * (s * NP2 + ry * NP + rx) + (isbg ? 0 : 1)];
        int base = isbg ? (2 * SNP2) : (2 * SNP2 + NS * NREC * NT);
        out_st(out, base + (s * NREC + r) * NT + (t - 1), val);
    }

    const int wid  = i >> 6;
    const int lane = i & 63;
    const int ip   = 60 * wid + lane - 2;              // pair index
    const bool inb   = (unsigned)ip < 222u;
    const bool owner = (lane >= 2) && (lane < 62) && inb;

    const int x0 = 2 * ip, x1 = x0 + 1;
    const float4 z4 = make_float4(0.f, 0.f, 0.f, 0.f);
    const float* wc = g_w[cur];

    float pbx0 = 0.f, pbx1 = 0.f, pax0 = 0.f, pax1 = 0.f;
    if (inb) {
        pbx0 = g_pb[x0]; pbx1 = g_pb[x1];
        pax0 = g_pa[x0]; pax1 = g_pa[x1];
    }
    const bool pxreg = (ip <= 11 || ip >= 210);

    if (!isframe) {
        // ---- interior: 3 rows per thread, 7 shared w-row loads ----
        const int idx0 = s * NP2 + y0 * NP + x0;
        float4 r0 = z4, r1 = z4, r2 = z4, r3 = z4, r4 = z4, r5 = z4, r6 = z4;
        if (inb) {
            r0 = *(const float4*)(wc + 2 * (idx0 - 2 * NP));
            r1 = *(const float4*)(wc + 2 * (idx0 - NP));
            r2 = *(const float4*)(wc + 2 * idx0);
            r3 = *(const float4*)(wc + 2 * (idx0 + NP));
            r4 = *(const float4*)(wc + 2 * (idx0 + 2 * NP));
            r5 = *(const float4*)(wc + 2 * (idx0 + 3 * NP));
            r6 = *(const float4*)(wc + 2 * (idx0 + 4 * NP));
        }
        row_interior(t, s, y0,     ip, inb, owner, pxreg, pbx0, pbx1, pax0, pax1,
                     r0, r1, r2, r3, r4, cur, nxt);
        row_interior(t, s, y0 + 1, ip, inb, owner, pxreg, pbx0, pbx1, pax0, pax1,
                     r1, r2, r3, r4, r5, cur, nxt);
        row_interior(t, s, y0 + 2, ip, inb, owner, pxreg, pbx0, pbx1, pax0, pax1,
                     r2, r3, r4, r5, r6, cur, nxt);
        return;
    }

    // ---- frame: R23/R19 single-row body (yframe always true here) ----
    const int y = y0;
    const int yx  = y * NP + x0;
    const int idx = s * NP2 + yx;

    float4 w4 = z4;
    if (inb) w4 = *(const float4*)(wc + 2 * idx);

    float4 wl = shup4(w4);
    float4 wr = shdn4(w4);

    float d2x_b0 = 0.f, d2x_b1 = 0.f, d2x_s0 = 0.f, d2x_s1 = 0.f;
    float4 pxn = z4;
    if (inb) {
        d2x_b0 = (C2A * (wl.x + wr.x) + C2B * (wl.z + w4.z) + C2C * w4.x) * INVH2;
        d2x_s0 = (C2A * (wl.y + wr.y) + C2B * (wl.w + w4.w) + C2C * w4.y) * INVH2;
        d2x_b1 = (C2A * (wl.z + wr.z) + C2B * (w4.x + wr.x) + C2C * w4.z) * INVH2;
        d2x_s1 = (C2A * (wl.w + wr.w) + C2B * (w4.y + wr.y) + C2C * w4.w) * INVH2;
        if (pxreg && pbx0 != 0.f) {
            float4 pxo = *(const float4*)(g_px[cur] + 2 * idx);
            float dwb0 = (C1A * wl.x - C1B * wl.z + C1B * w4.z - C1A * wr.x) * INVH;
            float dws0 = (C1A * wl.y - C1B * wl.w + C1B * w4.w - C1A * wr.y) * INVH;
            float dwb1 = (C1A * wl.z - C1B * w4.x + C1B * wr.x - C1A * wr.z) * INVH;
            float dws1 = (C1A * wl.w - C1B * w4.y + C1B * wr.y - C1A * wr.w) * INVH;
            pxn.x = pax0 * pxo.x + pbx0 * dwb0;
            pxn.y = pax0 * pxo.y + pbx0 * dws0;
            pxn.z = pax1 * pxo.z + pbx1 * dwb1;
            pxn.w = pax1 * pxo.w + pbx1 * dws1;
            if (owner)
                *(float4*)(g_px[nxt] + 2 * idx) = pxn;
        }
    }

    float dpx_b0 = 0.f, dpx_b1 = 0.f, dpx_s0 = 0.f, dpx_s1 = 0.f;
    {
        float4 pl = shup4(pxn);
        float4 pr = shdn4(pxn);
        if (pxreg) {
            dpx_b0 = (C1A * pl.x - C1B * pl.z + C1B * pxn.z - C1A * pr.x) * INVH;
            dpx_s0 = (C1A * pl.y - C1B * pl.w + C1B * pxn.w - C1A * pr.y) * INVH;
            dpx_b1 = (C1A * pl.z - C1B * pxn.x + C1B * pr.x - C1A * pr.z) * INVH;
            dpx_s1 = (C1A * pl.w - C1B * pxn.y + C1B * pr.y - C1A * pr.w) * INVH;
        }
    }
    if (!owner) return;

    const float pby = g_pb[y];
    float d2y_b0, d2y_b1, d2y_s0, d2y_s1;
    float dpy_b0 = 0.f, dpy_b1 = 0.f, dpy_s0 = 0.f, dpy_s1 = 0.f;
    {
        float4 wy[9];                        // rows y-4..y+4
        #pragma unroll
        for (int kk = 0; kk < 9; ++kk)
            wy[kk] = (kk == 4) ? w4 : ld4(wc, s, y - 4 + kk, ip);
        d2y_b0 = (C2A * (wy[2].x + wy[6].x) + C2B * (wy[3].x + wy[5].x) + C2C * wy[4].x) * INVH2;
        d2y_s0 = (C2A * (wy[2].y + wy[6].y) + C2B * (wy[3].y + wy[5].y) + C2C * wy[4].y) * INVH2;
        d2y_b1 = (C2A * (wy[2].z + wy[6].z) + C2B * (wy[3].z + wy[5].z) + C2C * wy[4].z) * INVH2;
        d2y_s1 = (C2A * (wy[2].w + wy[6].w) + C2B * (wy[3].w + wy[5].w) + C2C * wy[4].w) * INVH2;
        float4 pn[5];                        // psi_y_new rows y-2..y+2
        #pragma unroll
        for (int kk = 0; kk < 5; ++kk) {
            int yy = y - 2 + kk;
            float pbv = ((unsigned)yy < (unsigned)NP) ? g_pb[yy] : 0.f;  // uniform
            float4 r = z4;
            if (pbv != 0.f) {
                float pav = g_pa[yy];
                float4 po = *(const float4*)(g_py[cur] + 2 * (s * NP2 + yy * NP + x0));
                float db0 = (C1A * wy[kk].x - C1B * wy[kk+1].x + C1B * wy[kk+3].x - C1A * wy[kk+4].x) * INVH;
                float ds0 = (C1A * wy[kk].y - C1B * wy[kk+1].y + C1B * wy[kk+3].y - C1A * wy[kk+4].y) * INVH;
                float db1 = (C1A * wy[kk].z - C1B * wy[kk+1].z + C1B * wy[kk+3].z - C1A * wy[kk+4].z) * INVH;
                float ds1 = (C1A * wy[kk].w - C1B * wy[kk+1].w + C1B * wy[kk+3].w - C1A * wy[kk+4].w) * INVH;
                r.x = pav * po.x + pbv * db0;  r.y = pav * po.y + pbv * ds0;
                r.z = pav * po.z + pbv * db1;  r.w = pav * po.w + pbv * ds1;
            }
            pn[kk] = r;
        }
        dpy_b0 = (C1A * pn[0].x - C1B * pn[1].x + C1B * pn[3].x - C1A * pn[4].x) * INVH;
        dpy_s0 = (C1A * pn[0].y - C1B * pn[1].y + C1B * pn[3].y - C1A * pn[4].y) * INVH;
        dpy_b1 = (C1A * pn[0].z - C1B * pn[1].z + C1B * pn[3].z - C1A * pn[4].z) * INVH;
        dpy_s1 = (C1A * pn[0].w - C1B * pn[1].w + C1B * pn[3].w - C1A * pn[4].w) * INVH;
        if (pby != 0.f)
            *(float4*)(g_py[nxt] + 2 * idx) = pn[2];
    }

    float zy_b0 = 0.f, zy_b1 = 0.f, zy_s0 = 0.f, zy_s1 = 0.f;
    float zx_b0 = 0.f, zx_b1 = 0.f, zx_s0 = 0.f, zx_s1 = 0.f;
    if (pby != 0.f) {
        float pay = g_pa[y];
        float4 zo = *(const float4*)(g_zy + 2 * idx);
        zy_b0 = pay * zo.x + pby * (d2y_b0 + dpy_b0);
        zy_s0 = pay * zo.y + pby * (d2y_s0 + dpy_s0);
        zy_b1 = pay * zo.z + pby * (d2y_b1 + dpy_b1);
        zy_s1 = pay * zo.w + pby * (d2y_s1 + dpy_s1);
        *(float4*)(g_zy + 2 * idx) = make_float4(zy_b0, zy_s0, zy_b1, zy_s1);
    }
    if (pbx0 != 0.f) {
        float4 zo = *(const float4*)(g_zx + 2 * idx);
        zx_b0 = pax0 * zo.x + pbx0 * (d2x_b0 + dpx_b0);
        zx_s0 = pax0 * zo.y + pbx0 * (d2x_s0 + dpx_s0);
        zx_b1 = pax1 * zo.z + pbx1 * (d2x_b1 + dpx_b1);
        zx_s1 = pax1 * zo.w + pbx1 * (d2x_s1 + dpx_s1);
        *(float4*)(g_zx + 2 * idx) = make_float4(zx_b0, zx_s0, zx_b1, zx_s1);
    }

    float4 vb   = *(const float4*)(g_vb + 2 * yx);
    float4 prev = *(const float4*)(g_w[nxt] + 2 * idx);
    float lap_b0 = d2y_b0 + d2x_b0 + dpy_b0 + dpx_b0 + zy_b0 + zx_b0;
    float lap_s0 = d2y_s0 + d2x_s0 + dpy_s0 + dpx_s0 + zy_s0 + zx_s0;
    float lap_b1 = d2y_b1 + d2x_b1 + dpy_b1 + dpx_b1 + zy_b1 + zx_b1;
    float lap_s1 = d2y_s1 + d2x_s1 + dpy_s1 + dpx_s1 + zy_s1 + zx_s1;
    float wn_b0 = vb.x * lap_b0 + 2.f * w4.x - prev.x;
    float wn_s0 = vb.x * lap_s0 + 2.f * w4.y - prev.y + vb.y * lap_b0;
    float wn_b1 = vb.z * lap_b1 + 2.f * w4.z - prev.z;
    float wn_s1 = vb.z * lap_s1 + 2.f * w4.w - prev.w + vb.w * lap_b1;
    if (y == g_spos[2 * s]) {
        int sx = g_spos[2 * s + 1];
        if (sx == x0)      { wn_b0 += g_fbg[t * NS + s]; wn_s0 += g_fsc[t * NS + s]; }
        else if (sx == x1) { wn_b1 += g_fbg[t * NS + s]; wn_s1 += g_fsc[t * NS + s]; }
    }
    *(float4*)(g_w[nxt] + 2 * idx) = make_float4(wn_b0, wn_s0, wn_b1, wn_s1);
}

__global__ void finalize(const int* __restrict__ rloc, const int* __restrict__ rbloc,
                         void* __restrict__ out) {
    int i = blockIdx.x * blockDim.x + threadIdx.x;
    const float* w0 = g_w[0];     // NT even: newest field in buffer 0
    if (i < SNP2) {
        out_st(out, i,        w0[2 * i]);       // bg flat
        out_st(out, SNP2 + i, w0[2 * i + 1]);   // scattered flat
    }
    if (i < 2 * NS * NREC) {      // record last step (t = NT-1)
        bool isbg = i < NS * NREC;
        int k = isbg ? i : i - NS * NREC;
        int s = k / NREC, r = k % NREC;
        const int* rl = isbg ? rbloc : rloc;
        int ry = clampi(rl[(s * NREC + r) * 2 + 0], 0, NYX - 1) + PAD;
        int rx = clampi(rl[(s * NREC + r) * 2 + 1], 0, NYX - 1) + PAD;
        float val = w0[2 * (s * NP2 + ry * NP + rx) + (isbg ? 0 : 1)];
        int base = isbg ? (2 * SNP2) : (2 * SNP2 + NS * NREC * NT);
        out_st(out, base + (s * NREC + r) * NT + (NT - 1), val);
    }
}

extern "C" void kernel_launch(void* const* d_in, const int* in_sizes, int n_in,
                              void* d_out, int out_size, void* d_ws, size_t ws_size,
                              hipStream_t stream) {
    const void* v   = d_in[0];
    const void* sc  = d_in[1];
    const void* amp = d_in[2];
    const int* sloc  = (const int*)d_in[3];
    const int* rloc  = (const int*)d_in[4];
    const int* rbloc = (const int*)d_in[5];

    detect_mode<<<1, 64, 0, stream>>>(v);
    zero_state<<<(SNP2 / 2 + 255) / 256, 256, 0, stream>>>();
    prep_pad<<<(NP2 + 255) / 256, 256, 0, stream>>>(v, sc);
    prep_src<<<(NT * NS + 255) / 256, 256, 0, stream>>>(amp, sloc, v, sc);

    for (int t = 0; t < NT; ++t)
        step_fused<<<NBLK, 256, 0, stream>>>(t, rloc, rbloc, d_out);

    finalize<<<(SNP2 + 255) / 256, 256, 0, stream>>>(rloc, rbloc, d_out);
}